// Round 1
// baseline (53.836 us; speedup 1.0000x reference)
//
#include <hip/hip_runtime.h>
#include <math.h>

// Banded self-attention, fp32.
// B=4, T=4096, D=64, MASK_NUM=64 (fixed by reference setup_inputs()).
// One 64-lane wave per query row; 4 subgroups of 16 lanes each handle a
// different key s concurrently with independent online-softmax states,
// merged once at the end via xor-16/xor-32 butterfly.

constexpr int kB = 4;
constexpr int kT = 4096;
constexpr int kD = 64;
constexpr int kBand = 64;  // MASK_NUM

__global__ __launch_bounds__(256, 4) void band_attn_kernel(
    const float* __restrict__ Q,
    const float* __restrict__ K,
    const float* __restrict__ V,
    const int*   __restrict__ M,
    float* __restrict__ O)
{
    const int lane = threadIdx.x & 63;
    const int wid  = threadIdx.x >> 6;
    const int row  = (blockIdx.x << 2) + wid;     // row = b*T + t
    if (row >= kB * kT) return;
    const int b = row >> 12;                      // row / 4096
    const int t = row & (kT - 1);

    const int g = lane >> 4;      // subgroup 0..3 (which key in flight)
    const int r = lane & 15;      // dims 4r..4r+3

    const float4 qv = *reinterpret_cast<const float4*>(Q + (size_t)row * kD + 4 * r);

    // General mask semantics: allowed(t,s) = mask[b,s] && (band(t,s) || !mask[b,t])
    const int qm = M[row];
    int s_lo, s_hi;
    if (qm) {
        s_lo = t - kBand; if (s_lo < 0) s_lo = 0;
        s_hi = t + kBand; if (s_hi > kT - 1) s_hi = kT - 1;
    } else {
        s_lo = 0; s_hi = kT - 1;
    }

    float  m = -INFINITY;
    float  l = 0.0f;
    float4 acc = make_float4(0.0f, 0.0f, 0.0f, 0.0f);

    const float* kb = K + (size_t)b * kT * kD;
    const float* vb = V + (size_t)b * kT * kD;
    const int*   mb = M + b * kT;

    for (int s = s_lo + g; s <= s_hi; s += 4) {
        const float4 kv = *reinterpret_cast<const float4*>(kb + (size_t)s * kD + 4 * r);
        float p = qv.x * kv.x + qv.y * kv.y + qv.z * kv.z + qv.w * kv.w;
        // reduce within the 16-lane subgroup
        p += __shfl_xor(p, 1, 64);
        p += __shfl_xor(p, 2, 64);
        p += __shfl_xor(p, 4, 64);
        p += __shfl_xor(p, 8, 64);
        if (mb[s]) {
            const float sc  = p * 0.125f;            // / sqrt(64)
            const float mn  = fmaxf(m, sc);
            const float scl = __expf(m - mn);        // m=-inf first time -> 0
            const float w   = __expf(sc - mn);
            const float4 vv = *reinterpret_cast<const float4*>(vb + (size_t)s * kD + 4 * r);
            l     = l     * scl + w;
            acc.x = acc.x * scl + w * vv.x;
            acc.y = acc.y * scl + w * vv.y;
            acc.z = acc.z * scl + w * vv.z;
            acc.w = acc.w * scl + w * vv.w;
            m = mn;
        }
    }

    // Merge the 4 subgroup online-softmax states (butterfly over g).
    #pragma unroll
    for (int off = 16; off <= 32; off <<= 1) {
        const float m2 = __shfl_xor(m, off, 64);
        const float l2 = __shfl_xor(l, off, 64);
        float4 a2;
        a2.x = __shfl_xor(acc.x, off, 64);
        a2.y = __shfl_xor(acc.y, off, 64);
        a2.z = __shfl_xor(acc.z, off, 64);
        a2.w = __shfl_xor(acc.w, off, 64);
        const float mm = fmaxf(m, m2);
        const float e1 = __expf(m  - mm);
        const float e2 = __expf(m2 - mm);
        l     = l     * e1 + l2   * e2;
        acc.x = acc.x * e1 + a2.x * e2;
        acc.y = acc.y * e1 + a2.y * e2;
        acc.z = acc.z * e1 + a2.z * e2;
        acc.w = acc.w * e1 + a2.w * e2;
        m = mm;
    }

    if (g == 0) {
        const float inv = 1.0f / l;
        float4 o;
        o.x = acc.x * inv;
        o.y = acc.y * inv;
        o.z = acc.z * inv;
        o.w = acc.w * inv;
        *reinterpret_cast<float4*>(O + (size_t)row * kD + 4 * r) = o;
    }
}

extern "C" void kernel_launch(void* const* d_in, const int* in_sizes, int n_in,
                              void* d_out, int out_size, void* d_ws, size_t ws_size,
                              hipStream_t stream) {
    const float* q    = (const float*)d_in[0];
    const float* k    = (const float*)d_in[1];
    const float* v    = (const float*)d_in[2];
    const int*   mask = (const int*)d_in[3];
    float*       out  = (float*)d_out;

    const int rows = kB * kT;                 // 16384 query rows
    dim3 grid((rows + 3) / 4);                // 4 rows (waves) per block
    dim3 block(256);
    band_attn_kernel<<<grid, block, 0, stream>>>(q, k, v, mask, out);
}